// Round 1
// baseline (585.585 us; speedup 1.0000x reference)
//
#include <hip/hip_runtime.h>
#include <cstdint>

using u64 = unsigned long long;
using u32 = unsigned int;

// ---------------------------------------------------------------------------
// BN precompute: inv = g / sqrt(v + 1e-5), cc = b - m*inv  (match numpy rounding)
// ---------------------------------------------------------------------------
__global__ void bn_prep(const float* __restrict__ g, const float* __restrict__ b,
                        const float* __restrict__ m, const float* __restrict__ v,
                        int n, float* __restrict__ inv_out, float* __restrict__ cc_out) {
  int i = blockIdx.x * blockDim.x + threadIdx.x;
  if (i < n) {
    float inv = __fdiv_rn(g[i], __fsqrt_rn(__fadd_rn(v[i], 1e-5f)));
    inv_out[i] = inv;
    cc_out[i] = __fsub_rn(b[i], __fmul_rn(m[i], inv));
  }
}

// ---------------------------------------------------------------------------
// Pack sign(w) into bitmasks. w layout OIHW = [OC][IC][K] with K = kh*kw.
// wp bit = (w > 0); wz bit = (w == 0).  Output [OC][K][W] words, ic = wi*64+j.
// ---------------------------------------------------------------------------
__global__ void pack_w(const float* __restrict__ w, int OC, int IC, int K, int W,
                       u64* __restrict__ wp, u64* __restrict__ wz, u32* __restrict__ flag) {
  int idx = blockIdx.x * blockDim.x + threadIdx.x;   // (oc*K + t)*W + wi
  int total = OC * K * W;
  if (idx >= total) return;
  int wi = idx % W;
  int rest = idx / W;
  int t = rest % K;
  int oc = rest / K;
  u64 p = 0, z = 0;
  int icbase = wi * 64;
  int nb = IC - icbase; if (nb > 64) nb = 64;
  for (int j = 0; j < nb; ++j) {
    float f = w[((size_t)oc * IC + (icbase + j)) * K + t];
    if (f > 0.f) p |= (1ull << j);
    else if (f == 0.f) z |= (1ull << j);
  }
  wp[idx] = p;
  wz[idx] = z;
  if (z) atomicOr(flag, 1u);
}

// ---------------------------------------------------------------------------
// conv1 (fp32, 1->64ch, 3x3, stride2, pad1) + bias + BN threshold -> bit-pack
// x: [128][128][128], out a1p: [128][64][64] u64 (bit c = channel)
// ---------------------------------------------------------------------------
__global__ __launch_bounds__(256) void conv1_bin(
    const float* __restrict__ x, const float* __restrict__ w1, const float* __restrict__ b1,
    const float* __restrict__ inv1, const float* __restrict__ cc1,
    u64* __restrict__ a1p) {
  __shared__ float ws[64 * 9];
  __shared__ float bs[64], is_[64], cs[64];
  for (int i = threadIdx.x; i < 64 * 9; i += 256) ws[i] = w1[i];
  if (threadIdx.x < 64) {
    bs[threadIdx.x] = b1[threadIdx.x];
    is_[threadIdx.x] = inv1[threadIdx.x];
    cs[threadIdx.x] = cc1[threadIdx.x];
  }
  __syncthreads();
  int pix = blockIdx.x * 256 + threadIdx.x;    // 128*64*64 total
  int xo = pix & 63, yo = (pix >> 6) & 63, n = pix >> 12;
  const float* xin = x + (size_t)n * 128 * 128;
  float in[9];
#pragma unroll
  for (int ky = 0; ky < 3; ++ky) {
#pragma unroll
    for (int kx = 0; kx < 3; ++kx) {
      int iy = 2 * yo - 1 + ky, ix = 2 * xo - 1 + kx;   // max 127, only left/top pad
      in[ky * 3 + kx] = (iy >= 0 && ix >= 0) ? xin[iy * 128 + ix] : 0.f;
    }
  }
  u64 word = 0;
  for (int c = 0; c < 64; ++c) {
    float acc = 0.f;
#pragma unroll
    for (int t = 0; t < 9; ++t) acc += ws[c * 9 + t] * in[t];
    float h = __fadd_rn(acc, bs[c]);
    float bn = __fadd_rn(__fmul_rn(h, is_[c]), cs[c]);
    if (bn > 0.f) word |= (1ull << c);
  }
  a1p[pix] = word;
}

// ---------------------------------------------------------------------------
// Binarized 3x3 conv + BN threshold + pack.
// ain: [N][IN_HW][IN_HW][CINW] u64; wp/wz: [COUT][9][CINW]; aout: [N][OUT][OUT][COUTW]
// dot = 2*popc(A&Wp) - popc(A)  (+ popc(A&Wz) correction if any zero weight)
// ---------------------------------------------------------------------------
template <int CINW, int COUT, int COUTW, int STRIDE, int IN_HW, int OUT_HW>
__global__ __launch_bounds__(256) void bconv3x3(
    const u64* __restrict__ ain, const u64* __restrict__ wp, const u64* __restrict__ wz,
    const u32* __restrict__ flag, const float* __restrict__ inv, const float* __restrict__ cc,
    u64* __restrict__ aout) {
  __shared__ u64 wps[COUT * 9 * CINW];
  __shared__ float is_[COUT], cs[COUT];
  for (int i = threadIdx.x; i < COUT * 9 * CINW; i += 256) wps[i] = wp[i];
  for (int i = threadIdx.x; i < COUT; i += 256) { is_[i] = inv[i]; cs[i] = cc[i]; }
  __syncthreads();

  int pix = blockIdx.x * 256 + threadIdx.x;   // N*OUT_HW*OUT_HW, exact multiple of 256
  int xo = pix % OUT_HW;
  int rest = pix / OUT_HW;
  int yo = rest % OUT_HW;
  int n = rest / OUT_HW;

  u64 A[9 * CINW];
  int pa = 0;
#pragma unroll
  for (int ky = 0; ky < 3; ++ky) {
    int iy = STRIDE * yo - 1 + ky;
#pragma unroll
    for (int kx = 0; kx < 3; ++kx) {
      int ix = STRIDE * xo - 1 + kx;
      bool ok = (iy >= 0) && (iy < IN_HW) && (ix >= 0) && (ix < IN_HW);
#pragma unroll
      for (int w = 0; w < CINW; ++w) {
        u64 a = ok ? ain[(((size_t)n * IN_HW + iy) * IN_HW + ix) * CINW + w] : 0ull;
        A[(ky * 3 + kx) * CINW + w] = a;
        pa += __popcll(a);
      }
    }
  }

  bool anyz = (*flag != 0u);
  u64 wout[COUTW];
#pragma unroll
  for (int w = 0; w < COUTW; ++w) wout[w] = 0ull;

  for (int oc = 0; oc < COUT; ++oc) {
    int s = 0;
#pragma unroll
    for (int t = 0; t < 9 * CINW; ++t) s += __popcll(A[t] & wps[oc * 9 * CINW + t]);
    int val = 2 * s - pa;
    if (anyz) {
      for (int t = 0; t < 9 * CINW; ++t) val += __popcll(A[t] & wz[oc * 9 * CINW + t]);
    }
    float bn = __fadd_rn(__fmul_rn((float)val, is_[oc]), cs[oc]);
    if (bn > 0.f) wout[oc >> 6] |= (1ull << (oc & 63));
  }
#pragma unroll
  for (int w = 0; w < COUTW; ++w) aout[(size_t)pix * COUTW + w] = wout[w];
}

// ---------------------------------------------------------------------------
// conv5 (binarized 1x1, 192->192) + BN + ReLU + spatial sum.
// ain: [N][1024][3]; wp/wz: [192][3]; pool: [N][192] (sum over 1024 pixels)
// ---------------------------------------------------------------------------
__global__ __launch_bounds__(192) void bconv1x1_pool(
    const u64* __restrict__ ain, const u64* __restrict__ wp, const u64* __restrict__ wz,
    const u32* __restrict__ flag, const float* __restrict__ inv, const float* __restrict__ cc,
    float* __restrict__ pool) {
  int n = blockIdx.x;
  int oc = threadIdx.x;    // 192 threads
  u64 W0 = wp[oc * 3], W1 = wp[oc * 3 + 1], W2 = wp[oc * 3 + 2];
  bool anyz = (*flag != 0u);
  u64 Z0 = 0, Z1 = 0, Z2 = 0;
  if (anyz) { Z0 = wz[oc * 3]; Z1 = wz[oc * 3 + 1]; Z2 = wz[oc * 3 + 2]; }
  float iv = inv[oc], c0 = cc[oc];
  const u64* base = ain + (size_t)n * 1024 * 3;
  float acc = 0.f;
  for (int p = 0; p < 1024; ++p) {
    u64 a0 = base[p * 3], a1 = base[p * 3 + 1], a2 = base[p * 3 + 2];
    int s = __popcll(a0 & W0) + __popcll(a1 & W1) + __popcll(a2 & W2);
    int pa = __popcll(a0) + __popcll(a1) + __popcll(a2);
    int val = 2 * s - pa;
    if (anyz) val += __popcll(a0 & Z0) + __popcll(a1 & Z1) + __popcll(a2 & Z2);
    float bn = __fadd_rn(__fmul_rn((float)val, iv), c0);
    acc += fmaxf(bn, 0.f);
  }
  pool[n * 192 + oc] = acc;
}

// ---------------------------------------------------------------------------
// Head: mean-pool (sum/1024) -> conv6 (1x1, 192->12) + b6 -> FC -> softmax.
// mean commutes with the linear 1x1 conv, so no spatial work here.
// ---------------------------------------------------------------------------
__global__ __launch_bounds__(128) void head(
    const float* __restrict__ pool,   // [128][192] sums over 1024 pixels
    const float* __restrict__ w6,     // [12][192]
    const float* __restrict__ b6,     // [12]
    const float* __restrict__ fw,     // [12][12]
    const float* __restrict__ fb,     // [12]
    float* __restrict__ out) {        // [128][12]
  int n = threadIdx.x;
  if (n >= 128) return;
  float h6[12];
  for (int oc = 0; oc < 12; ++oc) {
    float s = 0.f;
    for (int c = 0; c < 192; ++c) s += pool[n * 192 + c] * w6[oc * 192 + c];
    h6[oc] = b6[oc] + s * (1.0f / 1024.0f);
  }
  float lg[12];
  float mx = -1e30f;
  for (int j = 0; j < 12; ++j) {
    float s = fb[j];
    for (int k = 0; k < 12; ++k) s += h6[k] * fw[j * 12 + k];
    lg[j] = s;
    mx = fmaxf(mx, s);
  }
  float se = 0.f;
  for (int j = 0; j < 12; ++j) { lg[j] = __expf(lg[j] - mx) ; se += lg[j]; }
  // use precise expf to track numpy closely
  se = 0.f;
  for (int j = 0; j < 12; ++j) { /* recompute with precise expf */ }
  // (overwritten below with precise path)
  float lg2[12]; se = 0.f;
  for (int j = 0; j < 12; ++j) {
    float s = fb[j];
    for (int k = 0; k < 12; ++k) s += h6[k] * fw[j * 12 + k];
    lg2[j] = expf(s - mx);
    se += lg2[j];
  }
  for (int j = 0; j < 12; ++j) out[n * 12 + j] = lg2[j] / se;
}

// ---------------------------------------------------------------------------
// Launch
// ---------------------------------------------------------------------------
extern "C" void kernel_launch(void* const* d_in, const int* in_sizes, int n_in,
                              void* d_out, int out_size, void* d_ws, size_t ws_size,
                              hipStream_t stream) {
  const float* x   = (const float*)d_in[0];
  const float* w1  = (const float*)d_in[1];
  const float* b1  = (const float*)d_in[2];
  const float* w2  = (const float*)d_in[3];
  const float* w3  = (const float*)d_in[4];
  const float* w4  = (const float*)d_in[5];
  const float* w5  = (const float*)d_in[6];
  const float* w6  = (const float*)d_in[7];
  const float* b6  = (const float*)d_in[8];
  const float* fcw = (const float*)d_in[9];
  const float* fcb = (const float*)d_in[10];
  const float* bng[5], *bnb[5], *bnm[5], *bnv[5];
  for (int l = 0; l < 5; ++l) {
    bng[l] = (const float*)d_in[11 + 4 * l + 0];
    bnb[l] = (const float*)d_in[11 + 4 * l + 1];
    bnm[l] = (const float*)d_in[11 + 4 * l + 2];
    bnv[l] = (const float*)d_in[11 + 4 * l + 3];
  }
  float* out = (float*)d_out;

  char* ws = (char*)d_ws;
  size_t off = 0;
  auto alloc = [&](size_t bytes) -> void* {
    void* p = ws + off;
    off += (bytes + 255) & ~(size_t)255;
    return p;
  };
  const int C[5] = {64, 128, 128, 192, 192};
  float* inv[5];
  float* cc[5];
  for (int l = 0; l < 5; ++l) {
    inv[l] = (float*)alloc(C[l] * 4);
    cc[l]  = (float*)alloc(C[l] * 4);
  }
  u64* wp2 = (u64*)alloc(128 * 9 * 1 * 8);
  u64* wz2 = (u64*)alloc(128 * 9 * 1 * 8);
  u64* wp3 = (u64*)alloc(128 * 9 * 2 * 8);
  u64* wz3 = (u64*)alloc(128 * 9 * 2 * 8);
  u64* wp4 = (u64*)alloc(192 * 9 * 2 * 8);
  u64* wz4 = (u64*)alloc(192 * 9 * 2 * 8);
  u64* wp5 = (u64*)alloc(192 * 1 * 3 * 8);
  u64* wz5 = (u64*)alloc(192 * 1 * 3 * 8);
  u32* flags = (u32*)alloc(4 * sizeof(u32));          // layer 2..5 zero-weight flags
  u64* a1p = (u64*)alloc((size_t)128 * 64 * 64 * 1 * 8);
  u64* a2p = (u64*)alloc((size_t)128 * 64 * 64 * 2 * 8);
  u64* a3p = (u64*)alloc((size_t)128 * 32 * 32 * 2 * 8);
  u64* a4p = (u64*)alloc((size_t)128 * 32 * 32 * 3 * 8);
  float* pool = (float*)alloc((size_t)128 * 192 * 4);
  (void)ws_size; (void)n_in; (void)in_sizes; (void)out_size;

  hipMemsetAsync(flags, 0, 4 * sizeof(u32), stream);

  // BN constants
  for (int l = 0; l < 5; ++l) {
    int n = C[l];
    bn_prep<<<(n + 255) / 256, 256, 0, stream>>>(bng[l], bnb[l], bnm[l], bnv[l], n, inv[l], cc[l]);
  }

  // Weight packing
  {
    int t2 = 128 * 9 * 1;
    pack_w<<<(t2 + 255) / 256, 256, 0, stream>>>(w2, 128, 64, 9, 1, wp2, wz2, flags + 0);
    int t3 = 128 * 9 * 2;
    pack_w<<<(t3 + 255) / 256, 256, 0, stream>>>(w3, 128, 128, 9, 2, wp3, wz3, flags + 1);
    int t4 = 192 * 9 * 2;
    pack_w<<<(t4 + 255) / 256, 256, 0, stream>>>(w4, 192, 128, 9, 2, wp4, wz4, flags + 2);
    int t5 = 192 * 1 * 3;
    pack_w<<<(t5 + 255) / 256, 256, 0, stream>>>(w5, 192, 192, 1, 3, wp5, wz5, flags + 3);
  }

  // conv1 + bin
  conv1_bin<<<(128 * 64 * 64) / 256, 256, 0, stream>>>(x, w1, b1, inv[0], cc[0], a1p);

  // conv2: 64ch(1w) -> 128ch(2w), 64x64, stride 1
  bconv3x3<1, 128, 2, 1, 64, 64><<<(128 * 64 * 64) / 256, 256, 0, stream>>>(
      a1p, wp2, wz2, flags + 0, inv[1], cc[1], a2p);

  // conv3: 128ch(2w) -> 128ch(2w), 64->32, stride 2
  bconv3x3<2, 128, 2, 2, 64, 32><<<(128 * 32 * 32) / 256, 256, 0, stream>>>(
      a2p, wp3, wz3, flags + 1, inv[2], cc[2], a3p);

  // conv4: 128ch(2w) -> 192ch(3w), 32x32, stride 1
  bconv3x3<2, 192, 3, 1, 32, 32><<<(128 * 32 * 32) / 256, 256, 0, stream>>>(
      a3p, wp4, wz4, flags + 2, inv[3], cc[3], a4p);

  // conv5 (1x1) + bn5 + relu + spatial sum
  bconv1x1_pool<<<128, 192, 0, stream>>>(a4p, wp5, wz5, flags + 3, inv[4], cc[4], pool);

  // head: mean -> conv6 -> fc -> softmax
  head<<<1, 128, 0, stream>>>(pool, w6, b6, fcw, fcb, out);
}

// Round 2
// 453.579 us; speedup vs baseline: 1.2910x; 1.2910x over previous
//
#include <hip/hip_runtime.h>
#include <cstdint>

using u64 = unsigned long long;
using u32 = unsigned int;

// ---------------------------------------------------------------------------
// Fused prep: BN constants for 5 layers + sign-packing of w2..w5.
// Thread space: [0,704) = BN elements, [704, 704+7488) = pack words.
// ---------------------------------------------------------------------------
struct PrepArgs {
  const float* bng[5]; const float* bnb[5]; const float* bnm[5]; const float* bnv[5];
  float* inv[5]; float* cc[5];
  const float* w[4];
  u64* wp[4]; u64* wz[4];
  u32* flags;   // one per packed layer
};

__global__ __launch_bounds__(256) void prep_all(PrepArgs a) {
  int i = blockIdx.x * 256 + threadIdx.x;
  if (i < 704) {
    const int off[6] = {0, 64, 192, 320, 512, 704};
    int l = 0;
    while (i >= off[l + 1]) ++l;
    int c = i - off[l];
    float inv = __fdiv_rn(a.bng[l][c], __fsqrt_rn(__fadd_rn(a.bnv[l][c], 1e-5f)));
    a.inv[l][c] = inv;
    a.cc[l][c] = __fsub_rn(a.bnb[l][c], __fmul_rn(a.bnm[l][c], inv));
    return;
  }
  int j = i - 704;
  if (j >= 7488) return;
  const int poff[5] = {0, 1152, 3456, 6912, 7488};
  const int OCt[4] = {128, 128, 192, 192};
  const int ICt[4] = {64, 128, 128, 192};
  const int Kt[4]  = {9, 9, 9, 1};
  const int Wt[4]  = {1, 2, 2, 3};
  int l = 0;
  while (j >= poff[l + 1]) ++l;
  int idx = j - poff[l];
  int W = Wt[l], K = Kt[l], IC = ICt[l];
  int wi = idx % W;
  int rest = idx / W;
  int t = rest % K;
  int oc = rest / K;
  u64 p = 0, z = 0;
  int icbase = wi * 64;
  int nb = IC - icbase; if (nb > 64) nb = 64;
  const float* w = a.w[l];
  for (int b = 0; b < nb; ++b) {
    float f = w[((size_t)oc * IC + (icbase + b)) * K + t];
    if (f > 0.f) p |= (1ull << b);
    else if (f == 0.f) z |= (1ull << b);
  }
  a.wp[l][idx] = p;
  a.wz[l][idx] = z;
  if (z) atomicOr(a.flags + l, 1u);
}

// ---------------------------------------------------------------------------
// conv1 (fp32, 1->64ch, 3x3, stride2, pad1) + bias + BN threshold -> bit-pack
// Weights read via wave-uniform global loads (scalar cache), no LDS.
// ---------------------------------------------------------------------------
__global__ __launch_bounds__(256) void conv1_bin(
    const float* __restrict__ x, const float* __restrict__ w1, const float* __restrict__ b1,
    const float* __restrict__ inv1, const float* __restrict__ cc1,
    u64* __restrict__ a1p) {
  int pix = blockIdx.x * 256 + threadIdx.x;    // 128*64*64 total
  int xo = pix & 63, yo = (pix >> 6) & 63, n = pix >> 12;
  const float* xin = x + (size_t)n * 128 * 128;
  float in[9];
#pragma unroll
  for (int ky = 0; ky < 3; ++ky) {
#pragma unroll
    for (int kx = 0; kx < 3; ++kx) {
      int iy = 2 * yo - 1 + ky, ix = 2 * xo - 1 + kx;   // max 127; only left/top pad
      in[ky * 3 + kx] = (iy >= 0 && ix >= 0) ? xin[iy * 128 + ix] : 0.f;
    }
  }
  u64 word = 0;
#pragma unroll 4
  for (int c = 0; c < 64; ++c) {
    float acc = 0.f;
#pragma unroll
    for (int t = 0; t < 9; ++t) acc += w1[c * 9 + t] * in[t];   // uniform -> s_load
    float h = __fadd_rn(acc, b1[c]);
    float bn = __fadd_rn(__fmul_rn(h, inv1[c]), cc1[c]);
    if (bn > 0.f) word |= (1ull << c);
  }
  a1p[pix] = word;
}

// ---------------------------------------------------------------------------
// Binarized 3x3 conv + BN threshold + pack. Weights via uniform global loads
// (s_load batches) — keeps the DS pipe idle, VALU does and/popcount only.
// dot = 2*popc(A&Wp) - popc(A)  (+ popc(A&Wz) correction if any zero weight)
// ---------------------------------------------------------------------------
template <int CINW, int COUT, int COUTW, int STRIDE, int IN_HW, int OUT_HW>
__global__ __launch_bounds__(256) void bconv3x3(
    const u64* __restrict__ ain, const u64* __restrict__ wp, const u64* __restrict__ wz,
    const u32* __restrict__ flag, const float* __restrict__ inv, const float* __restrict__ cc,
    u64* __restrict__ aout) {
  int pix = blockIdx.x * 256 + threadIdx.x;   // N*OUT_HW*OUT_HW, multiple of 256
  int xo = pix % OUT_HW;
  int rest = pix / OUT_HW;
  int yo = rest % OUT_HW;
  int n = rest / OUT_HW;

  u64 A[9 * CINW];
  int pa = 0;
#pragma unroll
  for (int ky = 0; ky < 3; ++ky) {
    int iy = STRIDE * yo - 1 + ky;
#pragma unroll
    for (int kx = 0; kx < 3; ++kx) {
      int ix = STRIDE * xo - 1 + kx;
      bool ok = (iy >= 0) && (iy < IN_HW) && (ix >= 0) && (ix < IN_HW);
#pragma unroll
      for (int w = 0; w < CINW; ++w) {
        u64 a = ok ? ain[(((size_t)n * IN_HW + iy) * IN_HW + ix) * CINW + w] : 0ull;
        A[(ky * 3 + kx) * CINW + w] = a;
        pa += __popcll(a);
      }
    }
  }

  bool anyz = (*flag != 0u);
  u64 wout[COUTW];
#pragma unroll
  for (int w = 0; w < COUTW; ++w) wout[w] = 0ull;

#pragma unroll 2
  for (int oc = 0; oc < COUT; ++oc) {
    const u64* wrow = wp + (size_t)oc * 9 * CINW;    // uniform -> s_load_dwordx16
    int s = 0;
#pragma unroll
    for (int t = 0; t < 9 * CINW; ++t) s += __popcll(A[t] & wrow[t]);
    int val = 2 * s - pa;
    if (anyz) {
      const u64* zrow = wz + (size_t)oc * 9 * CINW;
      for (int t = 0; t < 9 * CINW; ++t) val += __popcll(A[t] & zrow[t]);
    }
    float bn = __fadd_rn(__fmul_rn((float)val, inv[oc]), cc[oc]);
    if (bn > 0.f) wout[oc >> 6] |= (1ull << (oc & 63));
  }
  if (COUTW == 2) {
    *reinterpret_cast<ulonglong2*>(&aout[(size_t)pix * 2]) = make_ulonglong2(wout[0], wout[1]);
  } else {
#pragma unroll
    for (int w = 0; w < COUTW; ++w) aout[(size_t)pix * COUTW + w] = wout[w];
  }
}

// ---------------------------------------------------------------------------
// conv5 (binarized 1x1, 192->192) + BN + ReLU + partial spatial sum.
// Grid: 128 n * 16 chunks; 192 threads = one oc each, 64 pixels per block.
// Activation reads are wave-uniform (depend on pixel only) -> scalar loads.
// ---------------------------------------------------------------------------
#define NCH 16
#define CHUNK 64
__global__ __launch_bounds__(192) void bconv1x1_partial(
    const u64* __restrict__ ain, const u64* __restrict__ wp, const u64* __restrict__ wz,
    const u32* __restrict__ flag, const float* __restrict__ inv, const float* __restrict__ cc,
    float* __restrict__ partial) {
  int n = blockIdx.x / NCH, ch = blockIdx.x % NCH;
  int oc = threadIdx.x;    // 192 threads
  u64 W0 = wp[oc * 3], W1 = wp[oc * 3 + 1], W2 = wp[oc * 3 + 2];
  bool anyz = (*flag != 0u);
  u64 Z0 = 0, Z1 = 0, Z2 = 0;
  if (anyz) { Z0 = wz[oc * 3]; Z1 = wz[oc * 3 + 1]; Z2 = wz[oc * 3 + 2]; }
  float iv = inv[oc], c0 = cc[oc];
  const u64* base = ain + ((size_t)n * 1024 + ch * CHUNK) * 3;
  float acc = 0.f;
#pragma unroll 4
  for (int p = 0; p < CHUNK; ++p) {
    u64 a0 = base[p * 3], a1 = base[p * 3 + 1], a2 = base[p * 3 + 2];  // uniform -> s_load
    int s = __popcll(a0 & W0) + __popcll(a1 & W1) + __popcll(a2 & W2);
    int pa = __popcll(a0) + __popcll(a1) + __popcll(a2);
    int val = 2 * s - pa;
    if (anyz) val += __popcll(a0 & Z0) + __popcll(a1 & Z1) + __popcll(a2 & Z2);
    float bn = __fadd_rn(__fmul_rn((float)val, iv), c0);
    acc += fmaxf(bn, 0.f);
  }
  partial[((size_t)n * NCH + ch) * 192 + oc] = acc;
}

// Deterministic fixed-order reduce over the 16 chunks.
__global__ __launch_bounds__(256) void pool_reduce(
    const float* __restrict__ partial, float* __restrict__ pool) {
  int idx = blockIdx.x * 256 + threadIdx.x;   // 128*192 = 24576
  if (idx >= 128 * 192) return;
  int n = idx / 192, oc = idx % 192;
  float s = 0.f;
#pragma unroll
  for (int ch = 0; ch < NCH; ++ch) s += partial[((size_t)n * NCH + ch) * 192 + oc];
  pool[idx] = s;
}

// ---------------------------------------------------------------------------
// Head: mean (sum/1024) -> conv6 (1x1, 192->12) + b6 -> FC -> softmax.
// ---------------------------------------------------------------------------
__global__ __launch_bounds__(128) void head(
    const float* __restrict__ pool,   // [128][192] sums over 1024 pixels
    const float* __restrict__ w6,     // [12][192]
    const float* __restrict__ b6,     // [12]
    const float* __restrict__ fw,     // [12][12]
    const float* __restrict__ fb,     // [12]
    float* __restrict__ out) {        // [128][12]
  int n = threadIdx.x;
  if (n >= 128) return;
  float h6[12];
  for (int oc = 0; oc < 12; ++oc) {
    float s = 0.f;
    for (int c = 0; c < 192; ++c) s += pool[n * 192 + c] * w6[oc * 192 + c];
    h6[oc] = b6[oc] + s * (1.0f / 1024.0f);
  }
  float lg[12];
  float mx = -1e30f;
  for (int j = 0; j < 12; ++j) {
    float s = fb[j];
    for (int k = 0; k < 12; ++k) s += h6[k] * fw[j * 12 + k];
    lg[j] = s;
    mx = fmaxf(mx, s);
  }
  float se = 0.f;
  for (int j = 0; j < 12; ++j) { lg[j] = expf(lg[j] - mx); se += lg[j]; }
  for (int j = 0; j < 12; ++j) out[n * 12 + j] = lg[j] / se;
}

// ---------------------------------------------------------------------------
// Launch
// ---------------------------------------------------------------------------
extern "C" void kernel_launch(void* const* d_in, const int* in_sizes, int n_in,
                              void* d_out, int out_size, void* d_ws, size_t ws_size,
                              hipStream_t stream) {
  const float* x   = (const float*)d_in[0];
  const float* w1  = (const float*)d_in[1];
  const float* b1  = (const float*)d_in[2];
  const float* w2  = (const float*)d_in[3];
  const float* w3  = (const float*)d_in[4];
  const float* w4  = (const float*)d_in[5];
  const float* w5  = (const float*)d_in[6];
  const float* w6  = (const float*)d_in[7];
  const float* b6  = (const float*)d_in[8];
  const float* fcw = (const float*)d_in[9];
  const float* fcb = (const float*)d_in[10];
  float* out = (float*)d_out;

  char* ws = (char*)d_ws;
  size_t off = 0;
  auto alloc = [&](size_t bytes) -> void* {
    void* p = ws + off;
    off += (bytes + 255) & ~(size_t)255;
    return p;
  };
  const int C[5] = {64, 128, 128, 192, 192};
  float* inv[5];
  float* cc[5];
  for (int l = 0; l < 5; ++l) {
    inv[l] = (float*)alloc(C[l] * 4);
    cc[l]  = (float*)alloc(C[l] * 4);
  }
  u64* wp2 = (u64*)alloc(128 * 9 * 1 * 8);
  u64* wz2 = (u64*)alloc(128 * 9 * 1 * 8);
  u64* wp3 = (u64*)alloc(128 * 9 * 2 * 8);
  u64* wz3 = (u64*)alloc(128 * 9 * 2 * 8);
  u64* wp4 = (u64*)alloc(192 * 9 * 2 * 8);
  u64* wz4 = (u64*)alloc(192 * 9 * 2 * 8);
  u64* wp5 = (u64*)alloc(192 * 1 * 3 * 8);
  u64* wz5 = (u64*)alloc(192 * 1 * 3 * 8);
  u32* flags = (u32*)alloc(4 * sizeof(u32));
  u64* a1p = (u64*)alloc((size_t)128 * 64 * 64 * 1 * 8);
  u64* a2p = (u64*)alloc((size_t)128 * 64 * 64 * 2 * 8);
  u64* a3p = (u64*)alloc((size_t)128 * 32 * 32 * 2 * 8);
  u64* a4p = (u64*)alloc((size_t)128 * 32 * 32 * 3 * 8);
  float* partial = (float*)alloc((size_t)128 * NCH * 192 * 4);
  float* pool = (float*)alloc((size_t)128 * 192 * 4);
  (void)ws_size; (void)n_in; (void)in_sizes; (void)out_size;

  hipMemsetAsync(flags, 0, 4 * sizeof(u32), stream);

  // Fused BN-prep + weight packing (one launch)
  PrepArgs pa;
  const float* bsrc[4][5] = {};
  for (int l = 0; l < 5; ++l) {
    pa.bng[l] = (const float*)d_in[11 + 4 * l + 0];
    pa.bnb[l] = (const float*)d_in[11 + 4 * l + 1];
    pa.bnm[l] = (const float*)d_in[11 + 4 * l + 2];
    pa.bnv[l] = (const float*)d_in[11 + 4 * l + 3];
    pa.inv[l] = inv[l];
    pa.cc[l]  = cc[l];
  }
  (void)bsrc;
  pa.w[0] = w2; pa.w[1] = w3; pa.w[2] = w4; pa.w[3] = w5;
  pa.wp[0] = wp2; pa.wp[1] = wp3; pa.wp[2] = wp4; pa.wp[3] = wp5;
  pa.wz[0] = wz2; pa.wz[1] = wz3; pa.wz[2] = wz4; pa.wz[3] = wz5;
  pa.flags = flags;
  prep_all<<<32, 256, 0, stream>>>(pa);

  // conv1 + bin
  conv1_bin<<<(128 * 64 * 64) / 256, 256, 0, stream>>>(x, w1, b1, inv[0], cc[0], a1p);

  // conv2: 64ch(1w) -> 128ch(2w), 64x64, stride 1
  bconv3x3<1, 128, 2, 1, 64, 64><<<(128 * 64 * 64) / 256, 256, 0, stream>>>(
      a1p, wp2, wz2, flags + 0, inv[1], cc[1], a2p);

  // conv3: 128ch(2w) -> 128ch(2w), 64->32, stride 2
  bconv3x3<2, 128, 2, 2, 64, 32><<<(128 * 32 * 32) / 256, 256, 0, stream>>>(
      a2p, wp3, wz3, flags + 1, inv[2], cc[2], a3p);

  // conv4: 128ch(2w) -> 192ch(3w), 32x32, stride 1
  bconv3x3<2, 192, 3, 1, 32, 32><<<(128 * 32 * 32) / 256, 256, 0, stream>>>(
      a3p, wp4, wz4, flags + 2, inv[3], cc[3], a4p);

  // conv5 (1x1) + bn5 + relu + partial sums, then deterministic reduce
  bconv1x1_partial<<<128 * NCH, 192, 0, stream>>>(a4p, wp5, wz5, flags + 3, inv[4], cc[4], partial);
  pool_reduce<<<(128 * 192 + 255) / 256, 256, 0, stream>>>(partial, pool);

  // head: mean -> conv6 -> fc -> softmax
  head<<<1, 128, 0, stream>>>(pool, w6, b6, fcw, fcb, out);
}